// Round 17
// baseline (77.767 us; speedup 1.0000x reference)
//
#include <hip/hip_runtime.h>
#include <math.h>

#define B_N 32768
#define L_N 128
#define M_N 1024
#define NT 512
#define TB 64
#define TM 64
#define NCHUNK (M_N / TM)
#define NCH2 (NCHUNK / 2)

typedef __bf16 v8bf __attribute__((ext_vector_type(8)));
typedef __bf16 v4bf __attribute__((ext_vector_type(4)));
typedef float  v4f  __attribute__((ext_vector_type(4)));
typedef float  v2f  __attribute__((ext_vector_type(2)));
typedef unsigned int u32x2 __attribute__((ext_vector_type(2)));

#define MFMA(a, b, c) __builtin_amdgcn_mfma_f32_16x16x32_bf16(a, b, c, 0, 0, 0)

#define US  136   // u_bf [64][136] bf16
#define CNS 136   // c_n  [64][136] bf16
#define QSCALE 64.0f
#define QINV   0.015625f

__device__ inline v8bf pack8(float4 a, float4 b) {
    v8bf v;
    v[0] = (__bf16)a.x; v[1] = (__bf16)a.y; v[2] = (__bf16)a.z; v[3] = (__bf16)a.w;
    v[4] = (__bf16)b.x; v[5] = (__bf16)b.y; v[6] = (__bf16)b.z; v[7] = (__bf16)b.w;
    return v;
}

// ---------------- fused setup: transpose tiles (bx<32) + cpack (bx>=32) -----
__global__ void lebnn_setup(const float* __restrict__ centres,
                            const float* __restrict__ log_sigmas,
                            const float* __restrict__ lin_w,
                            float4* __restrict__ cpack,
                            __bf16* __restrict__ cT,
                            __bf16* __restrict__ cbn) {
    __shared__ __bf16 tile[64 * 72];
    const int bx = blockIdx.x;
    if (bx < 32) {
        const int m0 = (bx & 15) * 64;
        const int l0 = (bx >> 4) * 64;
        const int row = threadIdx.x >> 2;   // 0..63
        const int seg = threadIdx.x & 3;    // 16 elems each
        const float* src = centres + (size_t)(m0 + row) * L_N + l0 + seg * 16;
        float4 a0 = *(const float4*)(src);
        float4 a1 = *(const float4*)(src + 4);
        float4 a2 = *(const float4*)(src + 8);
        float4 a3 = *(const float4*)(src + 12);
        v8bf p0 = pack8(a0, a1);
        v8bf p1 = pack8(a2, a3);
        *(v8bf*)&tile[row * 72 + seg * 16]     = p0;
        *(v8bf*)&tile[row * 72 + seg * 16 + 8] = p1;
        __bf16* rdst = cbn + (size_t)(m0 + row) * L_N + l0 + seg * 16;
        *(v8bf*)(rdst)     = p0;
        *(v8bf*)(rdst + 8) = p1;
        __syncthreads();
        v8bf o0, o1;
#pragma unroll
        for (int i = 0; i < 8; ++i) o0[i] = tile[(seg * 16 + i) * 72 + row];
#pragma unroll
        for (int i = 0; i < 8; ++i) o1[i] = tile[(seg * 16 + 8 + i) * 72 + row];
        __bf16* dst = cT + (size_t)(l0 + row) * M_N + m0 + seg * 16;
        *(v8bf*)(dst)     = o0;
        *(v8bf*)(dst + 8) = o1;
    } else {
        int m = (bx - 32) * 256 + threadIdx.x;
        if (m < M_N) {
            const float4* row = (const float4*)(centres + (size_t)m * L_N);
            float s = 0.f;
#pragma unroll
            for (int i = 0; i < L_N / 4; ++i) {
                float4 v = row[i];
                s += v.x * v.x + v.y * v.y + v.z * v.z + v.w * v.w;
            }
            float4 p;
            p.x = s;
            p.y = expf(-2.f * log_sigmas[m]);
            p.z = lin_w[m];
            p.w = 0.f;
            cpack[m] = p;
        }
    }
}

// ---------------- Kernel A: r16 phase1 body, m-split (8 chunks/block) -------
// grid 1024: brow = bx>>1 picks the 64-row tile, mhalf = bx&1 picks chunks
// [mhalf*8, mhalf*8+8). Per-row s,R partials go to ws; finalize combines.
__global__ __launch_bounds__(NT) void lebnn_phase1(
    const float* __restrict__ u, const __bf16* __restrict__ cbn,
    const float4* __restrict__ cpack, unsigned int* __restrict__ qg32,
    float* __restrict__ sg_part, float* __restrict__ rg_part)
{
    __shared__ __bf16 u_bf[TB * US];
    __shared__ __bf16 c_n[TM * CNS];
    __shared__ float usq_s[TB];
    __shared__ float upart[TB * 9];
    __shared__ float sred[288];
    __shared__ float rred[288];

    const int tid  = threadIdx.x;
    const int w    = tid >> 6;
    const int lane = tid & 63;
    const int l15  = lane & 15;
    const int l4   = lane >> 4;
    const int bh   = w >> 2;
    const int mq   = w & 3;
    const int brow  = blockIdx.x >> 1;
    const int mhalf = blockIdx.x & 1;
    const int b0   = brow * TB;
    const int ch0  = mhalf * NCH2;

    // stage u (fp32 -> bf16) + row sumsq  (r3-verified)
    {
        int row = tid >> 3, seg = tid & 7;
        const float* up = u + (size_t)(b0 + row) * L_N + seg * 16;
        float4 a0 = *(const float4*)(up);
        float4 a1 = *(const float4*)(up + 4);
        float4 a2 = *(const float4*)(up + 8);
        float4 a3 = *(const float4*)(up + 12);
        float ps = a0.x*a0.x + a0.y*a0.y + a0.z*a0.z + a0.w*a0.w
                 + a1.x*a1.x + a1.y*a1.y + a1.z*a1.z + a1.w*a1.w
                 + a2.x*a2.x + a2.y*a2.y + a2.z*a2.z + a2.w*a2.w
                 + a3.x*a3.x + a3.y*a3.y + a3.z*a3.z + a3.w*a3.w;
        *(v8bf*)&u_bf[row * US + seg * 16]     = pack8(a0, a1);
        *(v8bf*)&u_bf[row * US + seg * 16 + 8] = pack8(a2, a3);
        upart[row * 9 + seg] = ps;
    }
    __syncthreads();
    if (tid < TB) {
        float s = 0.f;
#pragma unroll
        for (int i = 0; i < 8; ++i) s += upart[tid * 9 + i];
        usq_s[tid] = s;
    }
    __syncthreads();

    v8bf uf[2][4];
#pragma unroll
    for (int bt = 0; bt < 2; ++bt)
#pragma unroll
        for (int kk = 0; kk < 4; ++kk)
            uf[bt][kk] = *(v8bf*)&u_bf[(bh*32 + bt*16 + l15) * US + kk*32 + l4*8];

    float usq_r[2][4];
#pragma unroll
    for (int bt = 0; bt < 2; ++bt)
#pragma unroll
        for (int r = 0; r < 4; ++r)
            usq_r[bt][r] = usq_s[bh*32 + bt*16 + l4*4 + r];

    float s_p[2][4] = {{0.f,0.f,0.f,0.f},{0.f,0.f,0.f,0.f}};
    float r_p[2][4] = {{0.f,0.f,0.f,0.f},{0.f,0.f,0.f,0.f}};

    const int srow = tid >> 3;   // c_n staging row 0..63
    const int sseg = tid & 7;    // 16 elems each

    // prologue: first-chunk staging loads into regs (T14, r14/r16-verified)
    v8bf lda, ldb;
    {
        const __bf16* cp = cbn + (size_t)(ch0 * TM + srow) * L_N + sseg * 16;
        lda = *(const v8bf*)(cp);
        ldb = *(const v8bf*)(cp + 8);
    }

    for (int mt = 0; mt < NCH2; ++mt) {
        const int ch = ch0 + mt;
        const int m0 = ch * TM;
        __syncthreads();   // A: prev GEMM1 c_n reads done
        *(v8bf*)&c_n[srow * CNS + sseg * 16]     = lda;
        *(v8bf*)&c_n[srow * CNS + sseg * 16 + 8] = ldb;
        float4 cpv = cpack[m0 + mq*16 + l15];
        __syncthreads();   // B: c_n staged

        if (mt + 1 < NCH2) {
            const __bf16* cp = cbn + (size_t)(m0 + TM + srow) * L_N + sseg * 16;
            lda = *(const v8bf*)(cp);
            ldb = *(const v8bf*)(cp + 8);
        }

        v4f dot[2];
        dot[0] = (v4f){0.f,0.f,0.f,0.f};
        dot[1] = (v4f){0.f,0.f,0.f,0.f};
#pragma unroll
        for (int kk = 0; kk < 4; ++kk) {
            v8bf bfr = *(v8bf*)&c_n[(mq*16 + l15) * CNS + kk*32 + l4*8];
            dot[0] = MFMA(uf[0][kk], bfr, dot[0]);
            dot[1] = MFMA(uf[1][kk], bfr, dot[1]);
        }

        float qs[8];
        const float wqs = cpv.z * cpv.y * QSCALE;
#pragma unroll
        for (int bt = 0; bt < 2; ++bt) {
#pragma unroll
            for (int r = 0; r < 4; ++r) {
                float dv  = dot[bt][r];
                float raw = fmaf(-2.f, dv, usq_r[bt][r] + cpv.x);
                float x   = fmaf(fmaxf(raw, 0.f), cpv.y, 1.f);
                float ri  = rsqrtf(x);
                s_p[bt][r] = fmaf(cpv.z, x * ri, s_p[bt][r]);
                float qv  = (raw > 0.f) ? wqs * ri : 0.f;
                r_p[bt][r] += qv;
                qs[bt*4 + r] = qv;
            }
        }
        unsigned int w0 = 0, w1 = 0;
        w0 = __builtin_amdgcn_cvt_pk_fp8_f32(qs[0], qs[1], w0, false);
        w0 = __builtin_amdgcn_cvt_pk_fp8_f32(qs[2], qs[3], w0, true);
        w1 = __builtin_amdgcn_cvt_pk_fp8_f32(qs[4], qs[5], w1, false);
        w1 = __builtin_amdgcn_cvt_pk_fp8_f32(qs[6], qs[7], w1, true);
        u32x2 qw; qw[0] = w0; qw[1] = w1;
        *(u32x2*)(qg32 + ((size_t)brow * NCHUNK + ch) * (NT * 2) + tid * 2) = qw;
    }

    // reduce s, R over the 16-lane m-groups (r3-verified)
#pragma unroll
    for (int bt = 0; bt < 2; ++bt)
#pragma unroll
        for (int r = 0; r < 4; ++r) {
#pragma unroll
            for (int msk = 1; msk < 16; msk <<= 1) {
                s_p[bt][r] += __shfl_xor(s_p[bt][r], msk, 64);
                r_p[bt][r] += __shfl_xor(r_p[bt][r], msk, 64);
            }
        }
    if (l15 == 0) {
#pragma unroll
        for (int bt = 0; bt < 2; ++bt)
#pragma unroll
            for (int r = 0; r < 4; ++r) {
                sred[w*36 + bt*16 + l4*4 + r] = s_p[bt][r];
                rred[w*36 + bt*16 + l4*4 + r] = r_p[bt][r];
            }
    }
    __syncthreads();

    if (tid < TB) {
        int bhh = tid >> 5, rowr = tid & 31;
        float s = 0.f, R = 0.f;
#pragma unroll
        for (int i = 0; i < 4; ++i) {
            s += sred[(bhh*4 + i)*36 + rowr];
            R += rred[(bhh*4 + i)*36 + rowr];
        }
        sg_part[(size_t)mhalf * B_N + b0 + tid] = s;
        rg_part[(size_t)mhalf * B_N + b0 + tid] = R;
    }
}

// ---------------- finalize: combine the two m-half partials -> g, rs --------
__global__ __launch_bounds__(256) void lebnn_finalize(
    const float* __restrict__ sg_part, const float* __restrict__ rg_part,
    float* __restrict__ gg, float* __restrict__ rsg)
{
    int b = blockIdx.x * 256 + threadIdx.x;
    float s = sg_part[b] + sg_part[B_N + b];
    float R = rg_part[b] + rg_part[B_N + b];
    float g = (s > 0.f) ? 1.f : expf(s);
    gg[b]  = g;
    rsg[b] = fmaf(g * QINV, R, 1.f);   // R is 64x-scaled
}

// ---------------- Kernel B: T = q @ C (fp8 q), prefetch, fused epilogue -----
// (r13/r16 verbatim, hardware-verified)
__global__ __launch_bounds__(NT) void lebnn_gemm2(
    const float* __restrict__ u, const unsigned int* __restrict__ qg32,
    const __bf16* __restrict__ cT, const float* __restrict__ gg,
    const float* __restrict__ rsg, float* __restrict__ out)
{
    __shared__ __bf16 qt[64 * 72];
    __shared__ __bf16 ct[128 * 72];

    const int tid  = threadIdx.x;
    const int w    = tid >> 6;
    const int lane = tid & 63;
    const int l15  = lane & 15;
    const int l4   = lane >> 4;
    const int bh   = w >> 2;
    const int lq   = w & 3;
    const int bb0  = blockIdx.x * 64;
    const int lr   = tid >> 2;
    const int sg   = tid & 3;

    v4f acc[2][2];
#pragma unroll
    for (int bt = 0; bt < 2; ++bt)
#pragma unroll
        for (int lt = 0; lt < 2; ++lt)
            acc[bt][lt] = (v4f){0.f, 0.f, 0.f, 0.f};

    u32x2 qw = *(const u32x2*)(qg32 + ((size_t)blockIdx.x * NCHUNK + 0) * (NT * 2) + tid * 2);
    const __bf16* csrc = cT + (size_t)lr * M_N + sg * 16;
    v8bf cva = *(const v8bf*)(csrc);
    v8bf cvb = *(const v8bf*)(csrc + 8);

    for (int mt = 0; mt < NCHUNK; ++mt) {
        __syncthreads();
        {
            v2f p0 = __builtin_amdgcn_cvt_pk_f32_fp8(qw[0], false);
            v2f p1 = __builtin_amdgcn_cvt_pk_f32_fp8(qw[0], true);
            v2f p2 = __builtin_amdgcn_cvt_pk_f32_fp8(qw[1], false);
            v2f p3 = __builtin_amdgcn_cvt_pk_f32_fp8(qw[1], true);
            __bf16 qb[8];
            qb[0] = (__bf16)p0[0]; qb[1] = (__bf16)p0[1];
            qb[2] = (__bf16)p1[0]; qb[3] = (__bf16)p1[1];
            qb[4] = (__bf16)p2[0]; qb[5] = (__bf16)p2[1];
            qb[6] = (__bf16)p3[0]; qb[7] = (__bf16)p3[1];
#pragma unroll
            for (int bt = 0; bt < 2; ++bt)
#pragma unroll
                for (int r = 0; r < 4; ++r)
                    qt[(bh*32 + bt*16 + l4*4 + r) * 72 + lq*16 + l15] = qb[bt*4 + r];
            *(v8bf*)&ct[lr * 72 + sg * 16]     = cva;
            *(v8bf*)&ct[lr * 72 + sg * 16 + 8] = cvb;
        }
        __syncthreads();

        if (mt + 1 < NCHUNK) {
            qw = *(const u32x2*)(qg32 + ((size_t)blockIdx.x * NCHUNK + (mt+1)) * (NT * 2) + tid * 2);
            const __bf16* cn = cT + (size_t)lr * M_N + (mt+1) * TM + sg * 16;
            cva = *(const v8bf*)(cn);
            cvb = *(const v8bf*)(cn + 8);
        }

#pragma unroll
        for (int kk = 0; kk < 2; ++kk) {
            v8bf qa0 = *(v8bf*)&qt[(bh*32 +  0 + l15) * 72 + kk*32 + l4*8];
            v8bf qa1 = *(v8bf*)&qt[(bh*32 + 16 + l15) * 72 + kk*32 + l4*8];
#pragma unroll
            for (int lt = 0; lt < 2; ++lt) {
                v8bf cb = *(v8bf*)&ct[(lq*32 + lt*16 + l15) * 72 + kk*32 + l4*8];
                acc[0][lt] = MFMA(qa0, cb, acc[0][lt]);
                acc[1][lt] = MFMA(qa1, cb, acc[1][lt]);
            }
        }
    }

    float gv[2][4], rv[2][4];
#pragma unroll
    for (int bt = 0; bt < 2; ++bt)
#pragma unroll
        for (int r = 0; r < 4; ++r) {
            int b = bb0 + bh*32 + bt*16 + l4*4 + r;
            gv[bt][r] = gg[b] * QINV;
            rv[bt][r] = rsg[b];
        }
#pragma unroll
    for (int bt = 0; bt < 2; ++bt)
#pragma unroll
        for (int lt = 0; lt < 2; ++lt)
#pragma unroll
            for (int r = 0; r < 4; ++r) {
                size_t idx = (size_t)(bb0 + bh*32 + bt*16 + l4*4 + r) * L_N
                           + lq*32 + lt*16 + l15;
                out[idx] = fmaf(u[idx], rv[bt][r], -gv[bt][r] * acc[bt][lt][r]);
            }
}

// ================= FALLBACK: round-3 kernel, verbatim =================
#define CFS 68
#define OFF_UBF   0
#define OFF_CN    17408
#define OFF_CFL   34816
#define OFF_USQ   52224
#define OFF_UPART 52480
#define OFF_SRED  54784
#define OFF_RRED  55936
#define OFF_G     57088
#define OFF_RS    57344
#define SMEM_BYTES 57600

__global__ __launch_bounds__(NT) void lebnn_fallback(
    const float* __restrict__ u, const float* __restrict__ centres,
    const float4* __restrict__ cpack, float* __restrict__ out)
{
    extern __shared__ char smem[];
    __bf16* u_bf = (__bf16*)(smem + OFF_UBF);
    __bf16* c_n  = (__bf16*)(smem + OFF_CN);
    float*  cfl  = (float*)(smem + OFF_CFL);
    float* usq_s = (float*)(smem + OFF_USQ);
    float* upart = (float*)(smem + OFF_UPART);
    float* sred  = (float*)(smem + OFF_SRED);
    float* rred  = (float*)(smem + OFF_RRED);
    float* gsh   = (float*)(smem + OFF_G);
    float* rssh  = (float*)(smem + OFF_RS);

    const int tid  = threadIdx.x;
    const int w    = tid >> 6;
    const int lane = tid & 63;
    const int l15  = lane & 15;
    const int l4   = lane >> 4;
    const int bh   = w >> 2;
    const int mq   = w & 3;
    const int tx   = tid & 15;
    const int ty   = tid >> 4;
    const int b0   = blockIdx.x * 64;

    {
        int row = tid >> 3, seg = tid & 7;
        const float* up = u + (size_t)(b0 + row) * L_N + seg * 16;
        float4 a0 = *(const float4*)(up);
        float4 a1 = *(const float4*)(up + 4);
        float4 a2 = *(const float4*)(up + 8);
        float4 a3 = *(const float4*)(up + 12);
        float ps = a0.x*a0.x + a0.y*a0.y + a0.z*a0.z + a0.w*a0.w
                 + a1.x*a1.x + a1.y*a1.y + a1.z*a1.z + a1.w*a1.w
                 + a2.x*a2.x + a2.y*a2.y + a2.z*a2.z + a2.w*a2.w
                 + a3.x*a3.x + a3.y*a3.y + a3.z*a3.z + a3.w*a3.w;
        *(v8bf*)&u_bf[row * US + seg * 16]     = pack8(a0, a1);
        *(v8bf*)&u_bf[row * US + seg * 16 + 8] = pack8(a2, a3);
        upart[row * 9 + seg] = ps;
    }
    __syncthreads();
    if (tid < 64) {
        float s = 0.f;
#pragma unroll
        for (int i = 0; i < 8; ++i) s += upart[tid * 9 + i];
        usq_s[tid] = s;
    }
    __syncthreads();

    v8bf uf[2][4];
#pragma unroll
    for (int bt = 0; bt < 2; ++bt)
#pragma unroll
        for (int kk = 0; kk < 4; ++kk)
            uf[bt][kk] = *(v8bf*)&u_bf[(bh*32 + bt*16 + l15) * US + kk*32 + l4*8];

    float usq_r[2][4];
#pragma unroll
    for (int bt = 0; bt < 2; ++bt)
#pragma unroll
        for (int r = 0; r < 4; ++r)
            usq_r[bt][r] = usq_s[bh*32 + bt*16 + l4*4 + r];

    float s_p[2][4] = {{0.f,0.f,0.f,0.f},{0.f,0.f,0.f,0.f}};
    float r_p[2][4] = {{0.f,0.f,0.f,0.f},{0.f,0.f,0.f,0.f}};
    float T[4][4] = {{0.f}};

    const int rp = tid >> 4;
    const int cg = tid & 15;

    for (int mt = 0; mt < NCHUNK; ++mt) {
        const int m0 = mt * TM;
        __syncthreads();
        {
            const float* cp0 = centres + (size_t)(m0 + 2*rp) * L_N + cg * 8;
            float4 r0a = *(const float4*)(cp0);
            float4 r0b = *(const float4*)(cp0 + 4);
            float4 r1a = *(const float4*)(cp0 + L_N);
            float4 r1b = *(const float4*)(cp0 + L_N + 4);
            *(v8bf*)&c_n[(2*rp)     * CNS + cg*8] = pack8(r0a, r0b);
            *(v8bf*)&c_n[(2*rp + 1) * CNS + cg*8] = pack8(r1a, r1b);
        }
        float4 cpv = cpack[m0 + mq*16 + l15];
        __syncthreads();

        v4f dot[2];
        dot[0] = (v4f){0.f,0.f,0.f,0.f};
        dot[1] = (v4f){0.f,0.f,0.f,0.f};
#pragma unroll
        for (int kk = 0; kk < 4; ++kk) {
            v8bf bfr = *(v8bf*)&c_n[(mq*16 + l15) * CNS + kk*32 + l4*8];
            dot[0] = MFMA(uf[0][kk], bfr, dot[0]);
            dot[1] = MFMA(uf[1][kk], bfr, dot[1]);
        }

#pragma unroll
        for (int bt = 0; bt < 2; ++bt) {
#pragma unroll
            for (int r = 0; r < 4; ++r) {
                float dv  = dot[bt][r];
                float raw = fmaf(-2.f, dv, usq_r[bt][r] + cpv.x);
                float x   = fmaf(fmaxf(raw, 0.f), cpv.y, 1.f);
                float ri  = rsqrtf(x);
                s_p[bt][r] = fmaf(cpv.z, x * ri, s_p[bt][r]);
                float qv  = (raw > 0.f) ? cpv.z * cpv.y * ri : 0.f;
                r_p[bt][r] += qv;
                cfl[(mq*16 + l15) * CFS + bh*32 + bt*16 + l4*4 + r] = qv;
            }
        }
        __syncthreads();

        for (int mm = 0; mm < TM; ++mm) {
            v4f cf = *(v4f*)&cfl[mm * CFS + tx*4];
            v4bf cb = *(v4bf*)&c_n[mm * CNS + ty*4];
            float cv[4] = {(float)cb[0], (float)cb[1], (float)cb[2], (float)cb[3]};
#pragma unroll
            for (int i = 0; i < 4; ++i)
#pragma unroll
                for (int j = 0; j < 4; ++j)
                    T[i][j] = fmaf(cf[i], cv[j], T[i][j]);
        }
    }

    __syncthreads();

#pragma unroll
    for (int bt = 0; bt < 2; ++bt)
#pragma unroll
        for (int r = 0; r < 4; ++r) {
#pragma unroll
            for (int msk = 1; msk < 16; msk <<= 1) {
                s_p[bt][r] += __shfl_xor(s_p[bt][r], msk, 64);
                r_p[bt][r] += __shfl_xor(r_p[bt][r], msk, 64);
            }
        }
    if (l15 == 0) {
#pragma unroll
        for (int bt = 0; bt < 2; ++bt)
#pragma unroll
            for (int r = 0; r < 4; ++r) {
                sred[w*36 + bt*16 + l4*4 + r] = s_p[bt][r];
                rred[w*36 + bt*16 + l4*4 + r] = r_p[bt][r];
            }
    }
    __syncthreads();

    if (tid < 64) {
        int bhh = tid >> 5, rowr = tid & 31;
        float s = 0.f, R = 0.f;
#pragma unroll
        for (int i = 0; i < 4; ++i) {
            s += sred[(bhh*4 + i)*36 + rowr];
            R += rred[(bhh*4 + i)*36 + rowr];
        }
        float g = (s > 0.f) ? 1.f : expf(s);
        gsh[tid]  = g;
        rssh[tid] = fmaf(g, R, 1.f);
    }
    __syncthreads();

#pragma unroll
    for (int i = 0; i < 4; ++i) {
        int b = tx*4 + i;
        float rv = rssh[b];
        float gv = gsh[b];
        size_t idx = (size_t)(b0 + b) * L_N + ty*4;
        float4 uu = *(const float4*)(u + idx);
        float4 o;
        o.x = fmaf(uu.x, rv, -gv * T[i][0]);
        o.y = fmaf(uu.y, rv, -gv * T[i][1]);
        o.z = fmaf(uu.z, rv, -gv * T[i][2]);
        o.w = fmaf(uu.w, rv, -gv * T[i][3]);
        *(float4*)(out + idx) = o;
    }
}

extern "C" void kernel_launch(void* const* d_in, const int* in_sizes, int n_in,
                              void* d_out, int out_size, void* d_ws, size_t ws_size,
                              hipStream_t stream) {
    const float* u          = (const float*)d_in[0];
    const float* centres    = (const float*)d_in[1];
    const float* log_sigmas = (const float*)d_in[2];
    const float* lin_w      = (const float*)d_in[3];
    float* out = (float*)d_out;

    char* wsb = (char*)d_ws;
    float4* cpack = (float4*)wsb;                        //      16384 B
    __bf16* cT    = (__bf16*)(wsb + 16384);              //     262144 B
    __bf16* cbn   = (__bf16*)(wsb + 278528);             //     262144 B
    float*  gg    = (float*) (wsb + 540672);             //     131072 B
    float*  rsg   = (float*) (wsb + 671744);             //     131072 B
    unsigned int* qg32 = (unsigned int*)(wsb + 802816);  //   33554432 B (fp8 q)
    float* sg_part = (float*)(wsb + 802816 + 33554432);  //     262144 B (2 halves)
    float* rg_part = (float*)(wsb + 802816 + 33554432 + 262144); // 262144 B
    const size_t WS_NEED = 802816ULL + 33554432ULL + 524288ULL;

    lebnn_setup<<<36, 256, 0, stream>>>(centres, log_sigmas, lin_w, cpack, cT, cbn);

    if (ws_size >= WS_NEED) {
        lebnn_phase1<<<(B_N / TB) * 2, NT, 0, stream>>>(u, cbn, cpack, qg32, sg_part, rg_part);
        lebnn_finalize<<<B_N / 256, 256, 0, stream>>>(sg_part, rg_part, gg, rsg);
        lebnn_gemm2<<<B_N / 64, NT, 0, stream>>>(u, qg32, cT, gg, rsg, out);
    } else {
        hipFuncSetAttribute((const void*)lebnn_fallback,
                            hipFuncAttributeMaxDynamicSharedMemorySize, SMEM_BYTES);
        lebnn_fallback<<<B_N / 64, NT, SMEM_BYTES, stream>>>(u, centres, cpack, out);
    }
}

// Round 18
// 63.249 us; speedup vs baseline: 1.2295x; 1.2295x over previous
//
#include <hip/hip_runtime.h>
#include <math.h>

#define B_N 32768
#define L_N 128
#define M_N 1024
#define NT 512
#define TB 64
#define TM 64
#define NCHUNK (M_N / TM)

typedef __bf16 v8bf __attribute__((ext_vector_type(8)));
typedef __bf16 v4bf __attribute__((ext_vector_type(4)));
typedef float  v4f  __attribute__((ext_vector_type(4)));
typedef float  v2f  __attribute__((ext_vector_type(2)));
typedef unsigned int u32x2 __attribute__((ext_vector_type(2)));

#define MFMA(a, b, c) __builtin_amdgcn_mfma_f32_16x16x32_bf16(a, b, c, 0, 0, 0)

#define US  136   // u_bf [64][136] bf16
#define CNS 136   // c_n  [64][136] bf16
#define QSCALE 64.0f
#define QINV   0.015625f

__device__ inline v8bf pack8(float4 a, float4 b) {
    v8bf v;
    v[0] = (__bf16)a.x; v[1] = (__bf16)a.y; v[2] = (__bf16)a.z; v[3] = (__bf16)a.w;
    v[4] = (__bf16)b.x; v[5] = (__bf16)b.y; v[6] = (__bf16)b.z; v[7] = (__bf16)b.w;
    return v;
}

// ---------------- fused setup: transpose tiles (bx<32) + cpack (bx>=32) -----
__global__ void lebnn_setup(const float* __restrict__ centres,
                            const float* __restrict__ log_sigmas,
                            const float* __restrict__ lin_w,
                            float4* __restrict__ cpack,
                            __bf16* __restrict__ cT,
                            __bf16* __restrict__ cbn) {
    __shared__ __bf16 tile[64 * 72];
    const int bx = blockIdx.x;
    if (bx < 32) {
        const int m0 = (bx & 15) * 64;
        const int l0 = (bx >> 4) * 64;
        const int row = threadIdx.x >> 2;   // 0..63
        const int seg = threadIdx.x & 3;    // 16 elems each
        const float* src = centres + (size_t)(m0 + row) * L_N + l0 + seg * 16;
        float4 a0 = *(const float4*)(src);
        float4 a1 = *(const float4*)(src + 4);
        float4 a2 = *(const float4*)(src + 8);
        float4 a3 = *(const float4*)(src + 12);
        v8bf p0 = pack8(a0, a1);
        v8bf p1 = pack8(a2, a3);
        *(v8bf*)&tile[row * 72 + seg * 16]     = p0;
        *(v8bf*)&tile[row * 72 + seg * 16 + 8] = p1;
        __bf16* rdst = cbn + (size_t)(m0 + row) * L_N + l0 + seg * 16;
        *(v8bf*)(rdst)     = p0;
        *(v8bf*)(rdst + 8) = p1;
        __syncthreads();
        v8bf o0, o1;
#pragma unroll
        for (int i = 0; i < 8; ++i) o0[i] = tile[(seg * 16 + i) * 72 + row];
#pragma unroll
        for (int i = 0; i < 8; ++i) o1[i] = tile[(seg * 16 + 8 + i) * 72 + row];
        __bf16* dst = cT + (size_t)(l0 + row) * M_N + m0 + seg * 16;
        *(v8bf*)(dst)     = o0;
        *(v8bf*)(dst + 8) = o1;
    } else {
        int m = (bx - 32) * 256 + threadIdx.x;
        if (m < M_N) {
            const float4* row = (const float4*)(centres + (size_t)m * L_N);
            float s = 0.f;
#pragma unroll
            for (int i = 0; i < L_N / 4; ++i) {
                float4 v = row[i];
                s += v.x * v.x + v.y * v.y + v.z * v.z + v.w * v.w;
            }
            float4 p;
            p.x = s;
            p.y = expf(-2.f * log_sigmas[m]);
            p.z = lin_w[m];
            p.w = 0.f;
            cpack[m] = p;
        }
    }
}

// ---------------- Kernel A: r13 structure + T14 issue-early staging ---------
// (this exact phase1 passed in rounds 14 and 16, absmax 0.03125)
__global__ __launch_bounds__(NT) void lebnn_phase1(
    const float* __restrict__ u, const __bf16* __restrict__ cbn,
    const float4* __restrict__ cpack, unsigned int* __restrict__ qg32,
    float* __restrict__ gg, float* __restrict__ rsg)
{
    __shared__ __bf16 u_bf[TB * US];
    __shared__ __bf16 c_n[TM * CNS];
    __shared__ float usq_s[TB];
    __shared__ float upart[TB * 9];
    __shared__ float sred[288];
    __shared__ float rred[288];

    const int tid  = threadIdx.x;
    const int w    = tid >> 6;
    const int lane = tid & 63;
    const int l15  = lane & 15;
    const int l4   = lane >> 4;
    const int bh   = w >> 2;
    const int mq   = w & 3;
    const int b0   = blockIdx.x * TB;

    // stage u (fp32 -> bf16) + row sumsq  (r3-verified)
    {
        int row = tid >> 3, seg = tid & 7;
        const float* up = u + (size_t)(b0 + row) * L_N + seg * 16;
        float4 a0 = *(const float4*)(up);
        float4 a1 = *(const float4*)(up + 4);
        float4 a2 = *(const float4*)(up + 8);
        float4 a3 = *(const float4*)(up + 12);
        float ps = a0.x*a0.x + a0.y*a0.y + a0.z*a0.z + a0.w*a0.w
                 + a1.x*a1.x + a1.y*a1.y + a1.z*a1.z + a1.w*a1.w
                 + a2.x*a2.x + a2.y*a2.y + a2.z*a2.z + a2.w*a2.w
                 + a3.x*a3.x + a3.y*a3.y + a3.z*a3.z + a3.w*a3.w;
        *(v8bf*)&u_bf[row * US + seg * 16]     = pack8(a0, a1);
        *(v8bf*)&u_bf[row * US + seg * 16 + 8] = pack8(a2, a3);
        upart[row * 9 + seg] = ps;
    }
    __syncthreads();
    if (tid < TB) {
        float s = 0.f;
#pragma unroll
        for (int i = 0; i < 8; ++i) s += upart[tid * 9 + i];
        usq_s[tid] = s;
    }
    __syncthreads();

    v8bf uf[2][4];
#pragma unroll
    for (int bt = 0; bt < 2; ++bt)
#pragma unroll
        for (int kk = 0; kk < 4; ++kk)
            uf[bt][kk] = *(v8bf*)&u_bf[(bh*32 + bt*16 + l15) * US + kk*32 + l4*8];

    float usq_r[2][4];
#pragma unroll
    for (int bt = 0; bt < 2; ++bt)
#pragma unroll
        for (int r = 0; r < 4; ++r)
            usq_r[bt][r] = usq_s[bh*32 + bt*16 + l4*4 + r];

    float s_p[2][4] = {{0.f,0.f,0.f,0.f},{0.f,0.f,0.f,0.f}};
    float r_p[2][4] = {{0.f,0.f,0.f,0.f},{0.f,0.f,0.f,0.f}};

    const int srow = tid >> 3;   // c_n staging row 0..63
    const int sseg = tid & 7;    // 16 elems each

    // prologue: chunk-0 staging loads into regs
    v8bf lda, ldb;
    {
        const __bf16* cp = cbn + (size_t)srow * L_N + sseg * 16;
        lda = *(const v8bf*)(cp);
        ldb = *(const v8bf*)(cp + 8);
    }

    for (int mt = 0; mt < NCHUNK; ++mt) {
        const int m0 = mt * TM;
        __syncthreads();   // A: prev GEMM1 c_n reads done
        // tiny critical section: just the 2 ds_writes
        *(v8bf*)&c_n[srow * CNS + sseg * 16]     = lda;
        *(v8bf*)&c_n[srow * CNS + sseg * 16 + 8] = ldb;
        float4 cpv = cpack[m0 + mq*16 + l15];
        __syncthreads();   // B: c_n staged

        // issue next chunk's global loads (latency hidden under compute)
        if (mt + 1 < NCHUNK) {
            const __bf16* cp = cbn + (size_t)((mt+1)*TM + srow) * L_N + sseg * 16;
            lda = *(const v8bf*)(cp);
            ldb = *(const v8bf*)(cp + 8);
        }

        v4f dot[2];
        dot[0] = (v4f){0.f,0.f,0.f,0.f};
        dot[1] = (v4f){0.f,0.f,0.f,0.f};
#pragma unroll
        for (int kk = 0; kk < 4; ++kk) {
            v8bf bfr = *(v8bf*)&c_n[(mq*16 + l15) * CNS + kk*32 + l4*8];
            dot[0] = MFMA(uf[0][kk], bfr, dot[0]);
            dot[1] = MFMA(uf[1][kk], bfr, dot[1]);
        }

        float qs[8];
        const float wqs = cpv.z * cpv.y * QSCALE;
#pragma unroll
        for (int bt = 0; bt < 2; ++bt) {
#pragma unroll
            for (int r = 0; r < 4; ++r) {
                float dv  = dot[bt][r];
                float raw = fmaf(-2.f, dv, usq_r[bt][r] + cpv.x);
                float x   = fmaf(fmaxf(raw, 0.f), cpv.y, 1.f);
                float ri  = rsqrtf(x);
                s_p[bt][r] = fmaf(cpv.z, x * ri, s_p[bt][r]);
                float qv  = (raw > 0.f) ? wqs * ri : 0.f;
                r_p[bt][r] += qv;
                qs[bt*4 + r] = qv;
            }
        }
        unsigned int w0 = 0, w1 = 0;
        w0 = __builtin_amdgcn_cvt_pk_fp8_f32(qs[0], qs[1], w0, false);
        w0 = __builtin_amdgcn_cvt_pk_fp8_f32(qs[2], qs[3], w0, true);
        w1 = __builtin_amdgcn_cvt_pk_fp8_f32(qs[4], qs[5], w1, false);
        w1 = __builtin_amdgcn_cvt_pk_fp8_f32(qs[6], qs[7], w1, true);
        u32x2 qw; qw[0] = w0; qw[1] = w1;
        *(u32x2*)(qg32 + ((size_t)blockIdx.x * NCHUNK + mt) * (NT * 2) + tid * 2) = qw;
    }

    // reduce s, R (r3-verified)
#pragma unroll
    for (int bt = 0; bt < 2; ++bt)
#pragma unroll
        for (int r = 0; r < 4; ++r) {
#pragma unroll
            for (int msk = 1; msk < 16; msk <<= 1) {
                s_p[bt][r] += __shfl_xor(s_p[bt][r], msk, 64);
                r_p[bt][r] += __shfl_xor(r_p[bt][r], msk, 64);
            }
        }
    if (l15 == 0) {
#pragma unroll
        for (int bt = 0; bt < 2; ++bt)
#pragma unroll
            for (int r = 0; r < 4; ++r) {
                sred[w*36 + bt*16 + l4*4 + r] = s_p[bt][r];
                rred[w*36 + bt*16 + l4*4 + r] = r_p[bt][r];
            }
    }
    __syncthreads();

    if (tid < TB) {
        int bhh = tid >> 5, rowr = tid & 31;
        float s = 0.f, R = 0.f;
#pragma unroll
        for (int i = 0; i < 4; ++i) {
            s += sred[(bhh*4 + i)*36 + rowr];
            R += rred[(bhh*4 + i)*36 + rowr];
        }
        float g = (s > 0.f) ? 1.f : expf(s);
        gg[b0 + tid]  = g;
        rsg[b0 + tid] = fmaf(g * QINV, R, 1.f);
    }
}

// ---------------- Kernel B: T = q @ C (fp8 q), prefetch, fused epilogue -----
// (r13 verbatim, hardware-verified at 63.4 us)
__global__ __launch_bounds__(NT) void lebnn_gemm2(
    const float* __restrict__ u, const unsigned int* __restrict__ qg32,
    const __bf16* __restrict__ cT, const float* __restrict__ gg,
    const float* __restrict__ rsg, float* __restrict__ out)
{
    __shared__ __bf16 qt[64 * 72];
    __shared__ __bf16 ct[128 * 72];

    const int tid  = threadIdx.x;
    const int w    = tid >> 6;
    const int lane = tid & 63;
    const int l15  = lane & 15;
    const int l4   = lane >> 4;
    const int bh   = w >> 2;
    const int lq   = w & 3;
    const int bb0  = blockIdx.x * 64;
    const int lr   = tid >> 2;
    const int sg   = tid & 3;

    v4f acc[2][2];
#pragma unroll
    for (int bt = 0; bt < 2; ++bt)
#pragma unroll
        for (int lt = 0; lt < 2; ++lt)
            acc[bt][lt] = (v4f){0.f, 0.f, 0.f, 0.f};

    u32x2 qw = *(const u32x2*)(qg32 + ((size_t)blockIdx.x * NCHUNK + 0) * (NT * 2) + tid * 2);
    const __bf16* csrc = cT + (size_t)lr * M_N + sg * 16;
    v8bf cva = *(const v8bf*)(csrc);
    v8bf cvb = *(const v8bf*)(csrc + 8);

    for (int mt = 0; mt < NCHUNK; ++mt) {
        __syncthreads();
        {
            v2f p0 = __builtin_amdgcn_cvt_pk_f32_fp8(qw[0], false);
            v2f p1 = __builtin_amdgcn_cvt_pk_f32_fp8(qw[0], true);
            v2f p2 = __builtin_amdgcn_cvt_pk_f32_fp8(qw[1], false);
            v2f p3 = __builtin_amdgcn_cvt_pk_f32_fp8(qw[1], true);
            __bf16 qb[8];
            qb[0] = (__bf16)p0[0]; qb[1] = (__bf16)p0[1];
            qb[2] = (__bf16)p1[0]; qb[3] = (__bf16)p1[1];
            qb[4] = (__bf16)p2[0]; qb[5] = (__bf16)p2[1];
            qb[6] = (__bf16)p3[0]; qb[7] = (__bf16)p3[1];
#pragma unroll
            for (int bt = 0; bt < 2; ++bt)
#pragma unroll
                for (int r = 0; r < 4; ++r)
                    qt[(bh*32 + bt*16 + l4*4 + r) * 72 + lq*16 + l15] = qb[bt*4 + r];
            *(v8bf*)&ct[lr * 72 + sg * 16]     = cva;
            *(v8bf*)&ct[lr * 72 + sg * 16 + 8] = cvb;
        }
        __syncthreads();

        if (mt + 1 < NCHUNK) {
            qw = *(const u32x2*)(qg32 + ((size_t)blockIdx.x * NCHUNK + (mt+1)) * (NT * 2) + tid * 2);
            const __bf16* cn = cT + (size_t)lr * M_N + (mt+1) * TM + sg * 16;
            cva = *(const v8bf*)(cn);
            cvb = *(const v8bf*)(cn + 8);
        }

#pragma unroll
        for (int kk = 0; kk < 2; ++kk) {
            v8bf qa0 = *(v8bf*)&qt[(bh*32 +  0 + l15) * 72 + kk*32 + l4*8];
            v8bf qa1 = *(v8bf*)&qt[(bh*32 + 16 + l15) * 72 + kk*32 + l4*8];
#pragma unroll
            for (int lt = 0; lt < 2; ++lt) {
                v8bf cb = *(v8bf*)&ct[(lq*32 + lt*16 + l15) * 72 + kk*32 + l4*8];
                acc[0][lt] = MFMA(qa0, cb, acc[0][lt]);
                acc[1][lt] = MFMA(qa1, cb, acc[1][lt]);
            }
        }
    }

    float gv[2][4], rv[2][4];
#pragma unroll
    for (int bt = 0; bt < 2; ++bt)
#pragma unroll
        for (int r = 0; r < 4; ++r) {
            int b = bb0 + bh*32 + bt*16 + l4*4 + r;
            gv[bt][r] = gg[b] * QINV;
            rv[bt][r] = rsg[b];
        }
#pragma unroll
    for (int bt = 0; bt < 2; ++bt)
#pragma unroll
        for (int lt = 0; lt < 2; ++lt)
#pragma unroll
            for (int r = 0; r < 4; ++r) {
                size_t idx = (size_t)(bb0 + bh*32 + bt*16 + l4*4 + r) * L_N
                           + lq*32 + lt*16 + l15;
                out[idx] = fmaf(u[idx], rv[bt][r], -gv[bt][r] * acc[bt][lt][r]);
            }
}

// ================= FALLBACK: round-3 kernel, verbatim =================
#define CFS 68
#define OFF_UBF   0
#define OFF_CN    17408
#define OFF_CFL   34816
#define OFF_USQ   52224
#define OFF_UPART 52480
#define OFF_SRED  54784
#define OFF_RRED  55936
#define OFF_G     57088
#define OFF_RS    57344
#define SMEM_BYTES 57600

__global__ __launch_bounds__(NT) void lebnn_fallback(
    const float* __restrict__ u, const float* __restrict__ centres,
    const float4* __restrict__ cpack, float* __restrict__ out)
{
    extern __shared__ char smem[];
    __bf16* u_bf = (__bf16*)(smem + OFF_UBF);
    __bf16* c_n  = (__bf16*)(smem + OFF_CN);
    float*  cfl  = (float*)(smem + OFF_CFL);
    float* usq_s = (float*)(smem + OFF_USQ);
    float* upart = (float*)(smem + OFF_UPART);
    float* sred  = (float*)(smem + OFF_SRED);
    float* rred  = (float*)(smem + OFF_RRED);
    float* gsh   = (float*)(smem + OFF_G);
    float* rssh  = (float*)(smem + OFF_RS);

    const int tid  = threadIdx.x;
    const int w    = tid >> 6;
    const int lane = tid & 63;
    const int l15  = lane & 15;
    const int l4   = lane >> 4;
    const int bh   = w >> 2;
    const int mq   = w & 3;
    const int tx   = tid & 15;
    const int ty   = tid >> 4;
    const int b0   = blockIdx.x * 64;

    {
        int row = tid >> 3, seg = tid & 7;
        const float* up = u + (size_t)(b0 + row) * L_N + seg * 16;
        float4 a0 = *(const float4*)(up);
        float4 a1 = *(const float4*)(up + 4);
        float4 a2 = *(const float4*)(up + 8);
        float4 a3 = *(const float4*)(up + 12);
        float ps = a0.x*a0.x + a0.y*a0.y + a0.z*a0.z + a0.w*a0.w
                 + a1.x*a1.x + a1.y*a1.y + a1.z*a1.z + a1.w*a1.w
                 + a2.x*a2.x + a2.y*a2.y + a2.z*a2.z + a2.w*a2.w
                 + a3.x*a3.x + a3.y*a3.y + a3.z*a3.z + a3.w*a3.w;
        *(v8bf*)&u_bf[row * US + seg * 16]     = pack8(a0, a1);
        *(v8bf*)&u_bf[row * US + seg * 16 + 8] = pack8(a2, a3);
        upart[row * 9 + seg] = ps;
    }
    __syncthreads();
    if (tid < 64) {
        float s = 0.f;
#pragma unroll
        for (int i = 0; i < 8; ++i) s += upart[tid * 9 + i];
        usq_s[tid] = s;
    }
    __syncthreads();

    v8bf uf[2][4];
#pragma unroll
    for (int bt = 0; bt < 2; ++bt)
#pragma unroll
        for (int kk = 0; kk < 4; ++kk)
            uf[bt][kk] = *(v8bf*)&u_bf[(bh*32 + bt*16 + l15) * US + kk*32 + l4*8];

    float usq_r[2][4];
#pragma unroll
    for (int bt = 0; bt < 2; ++bt)
#pragma unroll
        for (int r = 0; r < 4; ++r)
            usq_r[bt][r] = usq_s[bh*32 + bt*16 + l4*4 + r];

    float s_p[2][4] = {{0.f,0.f,0.f,0.f},{0.f,0.f,0.f,0.f}};
    float r_p[2][4] = {{0.f,0.f,0.f,0.f},{0.f,0.f,0.f,0.f}};
    float T[4][4] = {{0.f}};

    const int rp = tid >> 4;
    const int cg = tid & 15;

    for (int mt = 0; mt < NCHUNK; ++mt) {
        const int m0 = mt * TM;
        __syncthreads();
        {
            const float* cp0 = centres + (size_t)(m0 + 2*rp) * L_N + cg * 8;
            float4 r0a = *(const float4*)(cp0);
            float4 r0b = *(const float4*)(cp0 + 4);
            float4 r1a = *(const float4*)(cp0 + L_N);
            float4 r1b = *(const float4*)(cp0 + L_N + 4);
            *(v8bf*)&c_n[(2*rp)     * CNS + cg*8] = pack8(r0a, r0b);
            *(v8bf*)&c_n[(2*rp + 1) * CNS + cg*8] = pack8(r1a, r1b);
        }
        float4 cpv = cpack[m0 + mq*16 + l15];
        __syncthreads();

        v4f dot[2];
        dot[0] = (v4f){0.f,0.f,0.f,0.f};
        dot[1] = (v4f){0.f,0.f,0.f,0.f};
#pragma unroll
        for (int kk = 0; kk < 4; ++kk) {
            v8bf bfr = *(v8bf*)&c_n[(mq*16 + l15) * CNS + kk*32 + l4*8];
            dot[0] = MFMA(uf[0][kk], bfr, dot[0]);
            dot[1] = MFMA(uf[1][kk], bfr, dot[1]);
        }

#pragma unroll
        for (int bt = 0; bt < 2; ++bt) {
#pragma unroll
            for (int r = 0; r < 4; ++r) {
                float dv  = dot[bt][r];
                float raw = fmaf(-2.f, dv, usq_r[bt][r] + cpv.x);
                float x   = fmaf(fmaxf(raw, 0.f), cpv.y, 1.f);
                float ri  = rsqrtf(x);
                s_p[bt][r] = fmaf(cpv.z, x * ri, s_p[bt][r]);
                float qv  = (raw > 0.f) ? cpv.z * cpv.y * ri : 0.f;
                r_p[bt][r] += qv;
                cfl[(mq*16 + l15) * CFS + bh*32 + bt*16 + l4*4 + r] = qv;
            }
        }
        __syncthreads();

        for (int mm = 0; mm < TM; ++mm) {
            v4f cf = *(v4f*)&cfl[mm * CFS + tx*4];
            v4bf cb = *(v4bf*)&c_n[mm * CNS + ty*4];
            float cv[4] = {(float)cb[0], (float)cb[1], (float)cb[2], (float)cb[3]};
#pragma unroll
            for (int i = 0; i < 4; ++i)
#pragma unroll
                for (int j = 0; j < 4; ++j)
                    T[i][j] = fmaf(cf[i], cv[j], T[i][j]);
        }
    }

    __syncthreads();

#pragma unroll
    for (int bt = 0; bt < 2; ++bt)
#pragma unroll
        for (int r = 0; r < 4; ++r) {
#pragma unroll
            for (int msk = 1; msk < 16; msk <<= 1) {
                s_p[bt][r] += __shfl_xor(s_p[bt][r], msk, 64);
                r_p[bt][r] += __shfl_xor(r_p[bt][r], msk, 64);
            }
        }
    if (l15 == 0) {
#pragma unroll
        for (int bt = 0; bt < 2; ++bt)
#pragma unroll
            for (int r = 0; r < 4; ++r) {
                sred[w*36 + bt*16 + l4*4 + r] = s_p[bt][r];
                rred[w*36 + bt*16 + l4*4 + r] = r_p[bt][r];
            }
    }
    __syncthreads();

    if (tid < 64) {
        int bhh = tid >> 5, rowr = tid & 31;
        float s = 0.f, R = 0.f;
#pragma unroll
        for (int i = 0; i < 4; ++i) {
            s += sred[(bhh*4 + i)*36 + rowr];
            R += rred[(bhh*4 + i)*36 + rowr];
        }
        float g = (s > 0.f) ? 1.f : expf(s);
        gsh[tid]  = g;
        rssh[tid] = fmaf(g, R, 1.f);
    }
    __syncthreads();

#pragma unroll
    for (int i = 0; i < 4; ++i) {
        int b = tx*4 + i;
        float rv = rssh[b];
        float gv = gsh[b];
        size_t idx = (size_t)(b0 + b) * L_N + ty*4;
        float4 uu = *(const float4*)(u + idx);
        float4 o;
        o.x = fmaf(uu.x, rv, -gv * T[i][0]);
        o.y = fmaf(uu.y, rv, -gv * T[i][1]);
        o.z = fmaf(uu.z, rv, -gv * T[i][2]);
        o.w = fmaf(uu.w, rv, -gv * T[i][3]);
        *(float4*)(out + idx) = o;
    }
}

extern "C" void kernel_launch(void* const* d_in, const int* in_sizes, int n_in,
                              void* d_out, int out_size, void* d_ws, size_t ws_size,
                              hipStream_t stream) {
    const float* u          = (const float*)d_in[0];
    const float* centres    = (const float*)d_in[1];
    const float* log_sigmas = (const float*)d_in[2];
    const float* lin_w      = (const float*)d_in[3];
    float* out = (float*)d_out;

    char* wsb = (char*)d_ws;
    float4* cpack = (float4*)wsb;                        //      16384 B
    __bf16* cT    = (__bf16*)(wsb + 16384);              //     262144 B
    __bf16* cbn   = (__bf16*)(wsb + 278528);             //     262144 B
    float*  gg    = (float*) (wsb + 540672);             //     131072 B
    float*  rsg   = (float*) (wsb + 671744);             //     131072 B
    unsigned int* qg32 = (unsigned int*)(wsb + 802816);  //   33554432 B (fp8 q)
    const size_t WS_NEED = 802816ULL + 33554432ULL;

    lebnn_setup<<<36, 256, 0, stream>>>(centres, log_sigmas, lin_w, cpack, cT, cbn);

    if (ws_size >= WS_NEED) {
        lebnn_phase1<<<B_N / TB, NT, 0, stream>>>(u, cbn, cpack, qg32, gg, rsg);
        lebnn_gemm2<<<B_N / 64, NT, 0, stream>>>(u, qg32, cT, gg, rsg, out);
    } else {
        hipFuncSetAttribute((const void*)lebnn_fallback,
                            hipFuncAttributeMaxDynamicSharedMemorySize, SMEM_BYTES);
        lebnn_fallback<<<B_N / 64, NT, SMEM_BYTES, stream>>>(u, centres, cpack, out);
    }
}